// Round 4
// baseline (1467.970 us; speedup 1.0000x reference)
//
#include <hip/hip_runtime.h>
#include <math.h>

// DP-means on MI355X — single persistent kernel, device-wide tree barrier.
// Round 4: grid 512 x 256 threads = 2 INDEPENDENT blocks/CU (launch_bounds
// (256,2), LDS 33 KB/block). Unlike round 3 (8 lockstep waves in one block,
// regressed), the two co-resident blocks overlap freely between grid
// barriers: one block's GEMM hides the other's L3 staging latency.
//   - phase A: 512 blocks x 128 pts; per-(p,k) fma chain BIT-IDENTICAL.
//   - phase D: 64 pt-groups x 8 dim-groups of 128; each (k,d) keeps its
//     exact 1024-pt fp32 chain and identical fp64 atomic set.
//   - musum/I2/E verbatim round-2 (guarded b<256 / b<64).
//   - staging keeps round-2's conflict-free (tid>>3) patterns.

#define NPTS   65536
#define DDIM   1024
#define KMAX   64
#define GRIDP  512
#define GRID   256
#define LAMBDA_F 1000.0f
#define INF_F  1e30f

struct Scal {
  int K, it, done, _p;
  double prev_obj;
  double s_all[2], s_far[2], sx2far[2];
  int farcnt[2];
  int counts[2][64];
};

// ---------------- barriers ----------------

// fallback: single-counter sense-reversal barrier (256 blocks)
__device__ __forceinline__ void gbarO(int* cnt, int* gen) {
  __syncthreads();
  if (threadIdx.x == 0) {
    __threadfence();
    int g = __hip_atomic_load(gen, __ATOMIC_RELAXED, __HIP_MEMORY_SCOPE_AGENT);
    int a = __hip_atomic_fetch_add(cnt, 1, __ATOMIC_ACQ_REL, __HIP_MEMORY_SCOPE_AGENT);
    if (a == GRID - 1) {
      __hip_atomic_store(cnt, 0, __ATOMIC_RELAXED, __HIP_MEMORY_SCOPE_AGENT);
      __hip_atomic_store(gen, g + 1, __ATOMIC_RELEASE, __HIP_MEMORY_SCOPE_AGENT);
    } else {
      while (__hip_atomic_load(gen, __ATOMIC_ACQUIRE, __HIP_MEMORY_SCOPE_AGENT) == g)
        __builtin_amdgcn_s_sleep(2);
    }
    __threadfence();
  }
  __syncthreads();
}

// tree barrier for 512 blocks: 32 leaves x 16 blocks, monotonic counters.
// leaf[i]=bar[i*32], root=bar[1024], gen=bar[1056]. r = 1-based round.
__device__ __forceinline__ void gbarP(int* bar, int b, int r) {
  __syncthreads();
  if (threadIdx.x == 0) {
    __threadfence();
    int* leaf = bar + ((b >> 4) << 5);
    int v = __hip_atomic_fetch_add(leaf, 1, __ATOMIC_ACQ_REL, __HIP_MEMORY_SCOPE_AGENT);
    if (v == (r << 4) - 1) {
      int w = __hip_atomic_fetch_add(bar + 1024, 1, __ATOMIC_ACQ_REL, __HIP_MEMORY_SCOPE_AGENT);
      if (w == (r << 5) - 1)
        __hip_atomic_store(bar + 1056, r, __ATOMIC_RELEASE, __HIP_MEMORY_SCOPE_AGENT);
    }
    while (__hip_atomic_load(bar + 1056, __ATOMIC_ACQUIRE, __HIP_MEMORY_SCOPE_AGENT) < r)
      __builtin_amdgcn_s_sleep(2);
    __threadfence();
  }
  __syncthreads();
}

__global__ void kInit(int* bar) { bar[threadIdx.x] = 0; bar[1024 + threadIdx.x] = 0; }

// ============================================================
// Phase A (512 blocks x 128 points). NKG = k's per k-group (2 groups).
// 8 thread-groups of 32 lanes = 4 point-subs (32 pts, 1 pt/lane) x 2
// k-groups. Coverage K <= 2*NKG. Per-(p,k) fma chain (chunk asc, d2 asc,
// x then y) identical to rounds 0-3 -> bit-identical distances/ties.
// ============================================================
template <int NKG>
__device__ __forceinline__ void phaseAP(
    const float* __restrict__ XT, const float* __restrict__ mu,
    const float* __restrict__ x2, int* __restrict__ z,
    const float* __restrict__ m2f, Scal* sc, char* smem,
    int b, int tid, int K, int Kc, int slot) {
  constexpr int LSTR = 34;
  constexpr int NK2 = 2 * NKG;
  constexpr int MUTOT = NK2 * 16;               // float2 elems in mu tile
  constexpr int MURND = (MUTOT + 255) / 256;

  float*  lX   = (float*)smem;             // 128*34*4 = 17408 B
  float*  lMu  = (float*)(smem + 17408);   // up to 64*34*4 = 8704 B
  double* wred = (double*)(smem + 26112);  //    96 B
  int*    wfc  = (int*)(smem + 26208);     //    16 B
  int*    lcnt = (int*)(smem + 26240);     //   256 B
  float*  rdm  = (float*)smem;             // reuse after GEMM: 128*2 floats
  int*    rkm  = (int*)(smem + 1024);

  const int lane = tid & 63, wv = tid >> 6;
  const int pg = tid & 31, tg = tid >> 5;
  const int kg = tg & 1, sub = tg >> 1;
  const int pbase = b << 7;
  const int pt = (sub << 5) + pg;               // 0..127
  const int jrow = tid >> 3, q = tid & 7;       // staging roles (2-way free)
  const bool kact = (kg * NKG) < K;

  if (tid < KMAX) lcnt[tid] = 0;

  float acc[NKG];
  #pragma unroll
  for (int j = 0; j < NKG; ++j) acc[j] = 0.f;

  float4 xr4[2];
  float2 mr[MURND];

  // prologue: prefetch chunk 0 (16KB X-tile: 2 float4/thread)
  #pragma unroll
  for (int i = 0; i < 2; ++i)
    xr4[i] = *(const float4*)&XT[(size_t)jrow * NPTS + pbase + (i << 6) + (q << 3) + 0];
  // note: (i<<6)+(q<<3) covers p in {0,8,...120} x2 rows of 8 -> rework below
  // -- replaced by 4x float4 over 128 pts:
  float4 xr4b[2];
  #pragma unroll
  for (int i = 0; i < 2; ++i)
    xr4b[i] = *(const float4*)&XT[(size_t)jrow * NPTS + pbase + (i << 6) + (q << 3) + 4];
  #pragma unroll
  for (int r = 0; r < MURND; ++r) {
    int idx = (r << 8) + tid;
    if (idx < MUTOT) {
      int k = idx >> 4, c2 = (idx & 15) << 1;
      mr[r] = *(const float2*)&mu[(k << 10) + c2];
    }
  }

  for (int dc = 0; dc < DDIM; dc += 32) {
    __syncthreads();
    #pragma unroll
    for (int i = 0; i < 2; ++i) {
      const int p = (i << 6) + (q << 3);
      lX[(p + 0) * LSTR + jrow] = xr4[i].x;
      lX[(p + 1) * LSTR + jrow] = xr4[i].y;
      lX[(p + 2) * LSTR + jrow] = xr4[i].z;
      lX[(p + 3) * LSTR + jrow] = xr4[i].w;
      lX[(p + 4) * LSTR + jrow] = xr4b[i].x;
      lX[(p + 5) * LSTR + jrow] = xr4b[i].y;
      lX[(p + 6) * LSTR + jrow] = xr4b[i].z;
      lX[(p + 7) * LSTR + jrow] = xr4b[i].w;
    }
    #pragma unroll
    for (int r = 0; r < MURND; ++r) {
      int idx = (r << 8) + tid;
      if (idx < MUTOT) {
        int k = idx >> 4, c2 = (idx & 15) << 1;
        *(float2*)&lMu[k * LSTR + c2] = mr[r];
      }
    }
    __syncthreads();
    // prefetch next chunk; latency hides under GEMM below (and under the
    // co-resident block's work).
    const int dcn = dc + 32;
    if (dcn < DDIM) {
      #pragma unroll
      for (int i = 0; i < 2; ++i)
        xr4[i] = *(const float4*)&XT[(size_t)(dcn + jrow) * NPTS + pbase + (i << 6) + (q << 3) + 0];
      #pragma unroll
      for (int i = 0; i < 2; ++i)
        xr4b[i] = *(const float4*)&XT[(size_t)(dcn + jrow) * NPTS + pbase + (i << 6) + (q << 3) + 4];
      #pragma unroll
      for (int r = 0; r < MURND; ++r) {
        int idx = (r << 8) + tid;
        if (idx < MUTOT) {
          int k = idx >> 4, c2 = (idx & 15) << 1;
          mr[r] = *(const float2*)&mu[(k << 10) + dcn + c2];
        }
      }
    }
    if (kact) {
      for (int d2 = 0; d2 < 16; ++d2) {
        float2 xa = *(const float2*)&lX[pt * LSTR + (d2 << 1)];
        #pragma unroll
        for (int j = 0; j < NKG; ++j) {
          float2 mv = *(const float2*)&lMu[(kg * NKG + j) * LSTR + (d2 << 1)];
          acc[j] = fmaf(xa.y, mv.y, fmaf(xa.x, mv.x, acc[j]));
        }
      }
    }
  }
  __syncthreads();  // last GEMM read lX; rdm/rkm reuse that region

  // per-group best (j ascending == k ascending -> same tie-break)
  {
    const float x2v = x2[pbase + pt];
    float bd2 = INF_F; int bk2 = KMAX;
    if (kact) {
      #pragma unroll
      for (int j = 0; j < NKG; ++j) {
        int k = kg * NKG + j;
        if (k < K) {
          float dist = x2v - 2.0f * acc[j] + m2f[k];
          if (dist < bd2) { bd2 = dist; bk2 = k; }
        }
      }
    }
    rdm[(pt << 1) + kg] = bd2;
    rkm[(pt << 1) + kg] = bk2;
  }
  __syncthreads();

  // merge the 2 groups; thread tid (<128) owns point pbase+tid.
  float bd = INF_F; int bk = KMAX; bool far = false;
  double a = 0.0, f = 0.0, xf = 0.0;
  if (tid < 128) {
    #pragma unroll
    for (int g = 0; g < 2; ++g) {
      float dv = rdm[(tid << 1) + g]; int kv = rkm[(tid << 1) + g];
      if (dv < bd || (dv == bd && kv < bk)) { bd = dv; bk = kv; }
    }
    far = bd > LAMBDA_F;
    const int zf = (far && (K < KMAX)) ? Kc : bk;
    z[pbase + tid] = zf;
    atomicAdd(&lcnt[zf], 1);
    const float x2p = x2[pbase + tid];
    a = (double)bd;
    f = far ? (double)bd : 0.0;
    xf = far ? (double)x2p : 0.0;
  }
  unsigned long long bal = __ballot(far);
  int fc = __popcll(bal);
  #pragma unroll
  for (int m = 1; m < 64; m <<= 1) {
    a += __shfl_xor(a, m); f += __shfl_xor(f, m); xf += __shfl_xor(xf, m);
  }
  if (lane == 0) { wred[wv] = a; wred[4 + wv] = f; wred[8 + wv] = xf; wfc[wv] = fc; }
  __syncthreads();
  if (tid == 0) {
    unsafeAtomicAdd(&sc->s_all[slot],  wred[0] + wred[1] + wred[2] + wred[3]);
    unsafeAtomicAdd(&sc->s_far[slot],  wred[4] + wred[5] + wred[6] + wred[7]);
    unsafeAtomicAdd(&sc->sx2far[slot], wred[8] + wred[9] + wred[10] + wred[11]);
    atomicAdd(&sc->farcnt[slot], wfc[0] + wfc[1] + wfc[2] + wfc[3]);
  }
  if (tid < KMAX) {
    int c = lcnt[tid];
    if (c > 0) atomicAdd(&sc->counts[slot][tid], c);
  }
}

__global__ __launch_bounds__(256, 2) void kMainP(
    const float* __restrict__ X, float* __restrict__ mu,
    float* __restrict__ x2, int* __restrict__ z,
    double* __restrict__ sums, double* __restrict__ musum,
    float* __restrict__ m2f, Scal* sc, int* bar, float* __restrict__ XT) {
  __shared__ __align__(16) char smem[33024];
  const int tid = threadIdx.x;
  const int b = blockIdx.x;
  const int lane = tid & 63, wv = tid >> 6;
  int rnd = 0;

  // ---- I0: zero persistent state ----
  if (b < 256) sums[(b << 8) + tid] = 0.0;
  if (b == 0) {
    if (tid < 64) { sc->counts[0][tid] = 0; sc->counts[1][tid] = 0; }
    if (tid == 0) {
      sc->K = 1; sc->it = 0; sc->done = 0; sc->prev_obj = 0.0;
      for (int s2 = 0; s2 < 2; ++s2) {
        sc->s_all[s2] = 0.0; sc->s_far[s2] = 0.0; sc->sx2far[s2] = 0.0; sc->farcnt[s2] = 0;
      }
    }
  }
  if (b == 1) {
    musum[tid] = 0.0; musum[256 + tid] = 0.0;
    musum[512 + tid] = 0.0; musum[768 + tid] = 0.0;
  }
  gbarP(bar, b, ++rnd);

  // ---- I1a: x2, 512 blocks x 128 pts (per-point chain exact) ----
  {
    const int pbase = b << 7;
    for (int i = 0; i < 32; ++i) {
      const int p = pbase + (i << 2) + wv;
      const float* row = X + ((size_t)p << 10);
      float s = 0.f;
      #pragma unroll
      for (int c = 0; c < 4; ++c) {
        float4 v = *(const float4*)&row[(c << 8) + (lane << 2)];
        s += v.x * v.x + v.y * v.y + v.z * v.z + v.w * v.w;
      }
      #pragma unroll
      for (int m = 1; m < 64; m <<= 1) s += __shfl_xor(s, m);
      if (lane == 0) x2[p] = s;
    }
  }

  // ---- I1t: build XT, 512 blocks x 128 pts (exact bit copies) ----
  {
    const int pbase = b << 7;
    const int jrow = tid >> 3, q = tid & 7;
    float* lX = (float*)smem;  // [128][34]
    for (int dc = 0; dc < DDIM; dc += 32) {
      __syncthreads();
      #pragma unroll
      for (int r = 0; r < 8; ++r) {
        int idx = (r << 8) + tid;
        int p = idx >> 4, c2 = (idx & 15) << 1;
        *(float2*)&lX[p * 34 + c2] =
            *(const float2*)&X[((size_t)(pbase + p) << 10) + dc + c2];
      }
      __syncthreads();
      #pragma unroll
      for (int i = 0; i < 2; ++i) {
        const int p = (i << 6) + (q << 3);
        float4 v, v2;
        v.x  = lX[(p + 0) * 34 + jrow];
        v.y  = lX[(p + 1) * 34 + jrow];
        v.z  = lX[(p + 2) * 34 + jrow];
        v.w  = lX[(p + 3) * 34 + jrow];
        v2.x = lX[(p + 4) * 34 + jrow];
        v2.y = lX[(p + 5) * 34 + jrow];
        v2.z = lX[(p + 6) * 34 + jrow];
        v2.w = lX[(p + 7) * 34 + jrow];
        *(float4*)&XT[(size_t)(dc + jrow) * NPTS + pbase + p] = v;
        *(float4*)&XT[(size_t)(dc + jrow) * NPTS + pbase + p + 4] = v2;
      }
    }
  }
  gbarP(bar, b, ++rnd);

  // ---- I1c: musum — EXACT round-2 code, blocks 0..255 only ----
  if (b < 256) {
    const int dcb = b & 3, nb = b >> 2;
    const int d = (dcb << 8) + tid;
    const float* xr = XT + (size_t)d * NPTS + ((size_t)nb << 10);
    float s = 0.f;
    for (int p4 = 0; p4 < 256; ++p4) {
      float4 v = *(const float4*)&xr[p4 << 2];
      s += v.x; s += v.y; s += v.z; s += v.w;
    }
    unsafeAtomicAdd(&musum[d], (double)s);
  }
  gbarP(bar, b, ++rnd);

  // ---- I2: mu[0]=mean, mu[k>0]=0, m2 (exact) ----
  if (b < KMAX) {
    double* w = (double*)smem;
    const int k = b;
    if (k == 0) {
      double ss = 0.0;
      #pragma unroll
      for (int r = 0; r < 4; ++r) {
        int d = (r << 8) + tid;
        float m = (float)(musum[d] * (1.0 / 65536.0));
        mu[d] = m;
        ss += (double)m * (double)m;
      }
      #pragma unroll
      for (int mk = 1; mk < 64; mk <<= 1) ss += __shfl_xor(ss, mk);
      if (lane == 0) w[wv] = ss;
      __syncthreads();
      if (tid == 0) m2f[0] = (float)(w[0] + w[1] + w[2] + w[3]);
    } else {
      #pragma unroll
      for (int r = 0; r < 4; ++r) mu[(k << 10) + (r << 8) + tid] = 0.f;
      if (tid == 0) m2f[k] = 0.f;
    }
  }
  gbarP(bar, b, ++rnd);

  // ---- main loop ----
  for (int t = 0; t < 50; ++t) {
    const int dn = *(volatile int*)&sc->done;
    if (dn) break;
    const int K = *(volatile int*)&sc->K;
    const int Kc = (K < KMAX - 1) ? K : (KMAX - 1);
    const int slot = t & 1;

    if (K <= 8)       phaseAP<4>(XT, mu, x2, z, m2f, sc, smem, b, tid, K, Kc, slot);
    else if (K <= 16) phaseAP<8>(XT, mu, x2, z, m2f, sc, smem, b, tid, K, Kc, slot);
    else if (K <= 32) phaseAP<16>(XT, mu, x2, z, m2f, sc, smem, b, tid, K, Kc, slot);
    else              phaseAP<32>(XT, mu, x2, z, m2f, sc, smem, b, tid, K, Kc, slot);
    gbarP(bar, b, ++rnd);

    // ---- Phase D: 64 pt-groups x 8 dim-groups of 128. Each (k,d) keeps
    // its exact 1024-pt fp32 chain + identical fp64 atomic set. ----
    {
      float (*accS)[128] = (float (*)[128])(void*)smem;  // 32 KB
      const int dcb = b & 7, nb = b >> 3;
      const int p0 = nb << 10;
      if (tid < 128) {
        #pragma unroll
        for (int k = 0; k < KMAX; ++k) accS[k][tid] = 0.f;
      }
      __syncthreads();
      if (tid < 128) {
        const float* xrow = XT + (size_t)((dcb << 7) + tid) * NPTS + p0;
        const int* zp = z + p0;
        #pragma unroll 8
        for (int p4 = 0; p4 < 256; ++p4) {
          float4 xc = *(const float4*)&xrow[p4 << 2];
          int4  zc = *(const int4*)&zp[p4 << 2];
          accS[zc.x][tid] += xc.x;
          accS[zc.y][tid] += xc.y;
          accS[zc.z][tid] += xc.z;
          accS[zc.w][tid] += xc.w;
        }
      }
      __syncthreads();
      if (tid < 128) {
        for (int k = 0; k < KMAX; ++k)
          if (sc->counts[slot][k] > 0)
            unsafeAtomicAdd(&sums[(k << 10) + (dcb << 7) + tid], (double)accS[k][tid]);
      }
    }
    gbarP(bar, b, ++rnd);

    // ---- Phase E: centroid means + m2 (exact); block Kc does epilogue ----
    if (b < KMAX) {
      double* w = (double*)smem;
      const int k = b;
      const int c = sc->counts[slot][k];
      const double inv = (c > 0) ? 1.0 / (double)c : 0.0;
      double ss = 0.0;
      #pragma unroll
      for (int r = 0; r < 4; ++r) {
        int d = (r << 8) + tid;
        float m = mu[(k << 10) + d];
        if (c > 0) m = (float)(sums[(k << 10) + d] * inv);
        mu[(k << 10) + d] = m;
        sums[(k << 10) + d] = 0.0;          // reset for next iteration
        ss += (double)m * (double)m;
      }
      #pragma unroll
      for (int mk = 1; mk < 64; mk <<= 1) ss += __shfl_xor(ss, mk);
      if (lane == 0) w[wv] = ss;
      __syncthreads();
      float m2k = 0.f;
      if (tid == 0) {
        m2k = (float)(w[0] + w[1] + w[2] + w[3]);
        m2f[k] = m2k;
      }
      if (k == Kc) {
        if (tid < 64) sc->counts[slot ^ 1][tid] = 0;
        if (tid == 0) {
          sc->s_all[slot ^ 1] = 0.0; sc->s_far[slot ^ 1] = 0.0;
          sc->sx2far[slot ^ 1] = 0.0; sc->farcnt[slot ^ 1] = 0;
          int farc = sc->farcnt[slot];
          int create = (farc > 0 && K < KMAX) ? 1 : 0;
          int Knew = K + create;
          double obj;
          if (create)
            obj = (sc->s_all[slot] - sc->s_far[slot]) +
                  (sc->sx2far[slot] - (double)farc * (double)m2k);
          else
            obj = sc->s_all[slot];
          obj += 1000.0 * (double)Knew;
          int conv = (sc->it > 0) && (fabs(obj - sc->prev_obj) < 1e-3 * obj);
          sc->done = conv;
          sc->prev_obj = obj;
          sc->K = Knew;
          sc->it = sc->it + 1;
        }
      }
    }
    gbarP(bar, b, ++rnd);
  }
}

// ============================================================
// FALLBACK: round-1 256-block kernel (used only if ws can't hold XT)
// ============================================================
template <int GP>
__device__ __forceinline__ void phaseAO(
    const float* __restrict__ X, const float* __restrict__ mu,
    const float* __restrict__ x2, int* __restrict__ z,
    const float* __restrict__ m2f, Scal* sc, char* smem,
    int b, int tid, int K, int Kc, int slot) {
  constexpr int LSTR = 34;
  constexpr int LGP = (GP == 1) ? 0 : (GP == 2) ? 1 : (GP == 4) ? 2 : 3;
  constexpr int MUTOT = GP * 128;
  constexpr int MURND = (MUTOT + 255) / 256;

  float*  lX   = (float*)smem;
  float*  lMu  = (float*)(smem + 34816);
  double* wred = (double*)(smem + 43520);
  int*    wfc  = (int*)(smem + 43616);
  int*    lcnt = (int*)(smem + 43648);
  float*  rdm  = (float*)smem;
  int*    rkm  = (int*)(smem + 9216);

  const int lane = tid & 63, wv = tid >> 6;
  const int pg = tid & 31, tg = tid >> 5;
  const int kg = tg & (GP - 1);
  const int sub = tg >> LGP;
  const int pbase = b << 8;
  const int p0loc = sub * (GP << 5);

  if (tid < KMAX) lcnt[tid] = 0;

  float acc[GP][8];
  #pragma unroll
  for (int i = 0; i < GP; ++i)
    #pragma unroll
    for (int j = 0; j < 8; ++j) acc[i][j] = 0.f;

  float2 xr[16];
  float2 mr[MURND];

  #pragma unroll
  for (int r = 0; r < 16; ++r) {
    int idx = (r << 8) + tid;
    int p = idx >> 4, c2 = (idx & 15) << 1;
    xr[r] = *(const float2*)&X[((size_t)(pbase + p) << 10) + c2];
  }
  #pragma unroll
  for (int r = 0; r < MURND; ++r) {
    int idx = (r << 8) + tid;
    if (idx < MUTOT) {
      int k = idx >> 4, c2 = (idx & 15) << 1;
      mr[r] = *(const float2*)&mu[(k << 10) + c2];
    }
  }

  for (int dc = 0; dc < DDIM; dc += 32) {
    __syncthreads();
    #pragma unroll
    for (int r = 0; r < 16; ++r) {
      int idx = (r << 8) + tid;
      int p = idx >> 4, c2 = (idx & 15) << 1;
      *(float2*)&lX[p * LSTR + c2] = xr[r];
    }
    #pragma unroll
    for (int r = 0; r < MURND; ++r) {
      int idx = (r << 8) + tid;
      if (idx < MUTOT) {
        int k = idx >> 4, c2 = (idx & 15) << 1;
        *(float2*)&lMu[k * LSTR + c2] = mr[r];
      }
    }
    __syncthreads();
    const int dcn = dc + 32;
    if (dcn < DDIM) {
      #pragma unroll
      for (int r = 0; r < 16; ++r) {
        int idx = (r << 8) + tid;
        int p = idx >> 4, c2 = (idx & 15) << 1;
        xr[r] = *(const float2*)&X[((size_t)(pbase + p) << 10) + dcn + c2];
      }
      #pragma unroll
      for (int r = 0; r < MURND; ++r) {
        int idx = (r << 8) + tid;
        if (idx < MUTOT) {
          int k = idx >> 4, c2 = (idx & 15) << 1;
          mr[r] = *(const float2*)&mu[(k << 10) + dcn + c2];
        }
      }
    }
    for (int d2 = 0; d2 < 16; ++d2) {
      float2 ma[8], xa[GP];
      #pragma unroll
      for (int j = 0; j < 8; ++j)
        ma[j] = *(const float2*)&lMu[((kg << 3) + j) * LSTR + (d2 << 1)];
      #pragma unroll
      for (int i = 0; i < GP; ++i)
        xa[i] = *(const float2*)&lX[(p0loc + (i << 5) + pg) * LSTR + (d2 << 1)];
      #pragma unroll
      for (int i = 0; i < GP; ++i)
        #pragma unroll
        for (int j = 0; j < 8; ++j)
          acc[i][j] = fmaf(xa[i].y, ma[j].y, fmaf(xa[i].x, ma[j].x, acc[i][j]));
    }
  }
  __syncthreads();

  float m2v[8];
  #pragma unroll
  for (int j = 0; j < 8; ++j) m2v[j] = m2f[(kg << 3) + j];
  float x2v[GP];
  #pragma unroll
  for (int i = 0; i < GP; ++i) x2v[i] = x2[pbase + p0loc + (i << 5) + pg];

  #pragma unroll
  for (int i = 0; i < GP; ++i) {
    float bd2 = INF_F; int bk2 = KMAX;
    #pragma unroll
    for (int j = 0; j < 8; ++j) {
      int k = (kg << 3) + j;
      if (k < K) {
        float dist = x2v[i] - 2.0f * acc[i][j] + m2v[j];
        if (dist < bd2) { bd2 = dist; bk2 = k; }
      }
    }
    const int pl = p0loc + (i << 5) + pg;
    rdm[pl * 9 + kg] = bd2;
    rkm[pl * 9 + kg] = bk2;
  }
  __syncthreads();

  float bd = INF_F; int bk = KMAX;
  #pragma unroll
  for (int g = 0; g < GP; ++g) {
    float dv = rdm[tid * 9 + g]; int kv = rkm[tid * 9 + g];
    if (dv < bd || (dv == bd && kv < bk)) { bd = dv; bk = kv; }
  }

  const bool far = bd > LAMBDA_F;
  const int zf = (far && (K < KMAX)) ? Kc : bk;
  z[pbase + tid] = zf;
  atomicAdd(&lcnt[zf], 1);

  const float x2p = x2[pbase + tid];
  double a = (double)bd;
  double f = far ? (double)bd : 0.0;
  double xf = far ? (double)x2p : 0.0;
  unsigned long long bal = __ballot(far);
  int fc = __popcll(bal);
  #pragma unroll
  for (int m = 1; m < 64; m <<= 1) {
    a += __shfl_xor(a, m); f += __shfl_xor(f, m); xf += __shfl_xor(xf, m);
  }
  if (lane == 0) { wred[wv] = a; wred[4 + wv] = f; wred[8 + wv] = xf; wfc[wv] = fc; }
  __syncthreads();
  if (tid == 0) {
    unsafeAtomicAdd(&sc->s_all[slot],  wred[0] + wred[1] + wred[2] + wred[3]);
    unsafeAtomicAdd(&sc->s_far[slot],  wred[4] + wred[5] + wred[6] + wred[7]);
    unsafeAtomicAdd(&sc->sx2far[slot], wred[8] + wred[9] + wred[10] + wred[11]);
    atomicAdd(&sc->farcnt[slot], wfc[0] + wfc[1] + wfc[2] + wfc[3]);
  }
  if (tid < KMAX) {
    int c = lcnt[tid];
    if (c > 0) atomicAdd(&sc->counts[slot][tid], c);
  }
}

__global__ __launch_bounds__(256, 1) void kMainOld(
    const float* __restrict__ X, float* __restrict__ mu,
    float* __restrict__ x2, int* __restrict__ z,
    double* __restrict__ sums, double* __restrict__ musum,
    float* __restrict__ m2f, Scal* sc, int* bar) {
  __shared__ __align__(16) char smem[65536];
  const int tid = threadIdx.x;
  const int b = blockIdx.x;
  const int lane = tid & 63, wv = tid >> 6;
  int* bcnt = bar;
  int* bgen = bar + 32;

  sums[(b << 8) + tid] = 0.0;
  if (b == 0) {
    if (tid < 64) { sc->counts[0][tid] = 0; sc->counts[1][tid] = 0; }
    if (tid == 0) {
      sc->K = 1; sc->it = 0; sc->done = 0; sc->prev_obj = 0.0;
      for (int s2 = 0; s2 < 2; ++s2) {
        sc->s_all[s2] = 0.0; sc->s_far[s2] = 0.0; sc->sx2far[s2] = 0.0; sc->farcnt[s2] = 0;
      }
    }
  }
  if (b == 1) {
    musum[tid] = 0.0; musum[256 + tid] = 0.0;
    musum[512 + tid] = 0.0; musum[768 + tid] = 0.0;
  }
  gbarO(bcnt, bgen);

  {
    const int pbase = b << 8;
    for (int i = 0; i < 64; ++i) {
      const int p = pbase + (i << 2) + wv;
      const float* row = X + ((size_t)p << 10);
      float s = 0.f;
      #pragma unroll
      for (int c = 0; c < 4; ++c) {
        float4 v = *(const float4*)&row[(c << 8) + (lane << 2)];
        s += v.x * v.x + v.y * v.y + v.z * v.z + v.w * v.w;
      }
      #pragma unroll
      for (int m = 1; m < 64; m <<= 1) s += __shfl_xor(s, m);
      if (lane == 0) x2[p] = s;
    }
    const int dcb = b & 3, nb = b >> 2;
    const int d = (dcb << 8) + tid;
    const float* xp = X + ((size_t)nb << 20) + d;
    float s = 0.f;
    for (int p = 0; p < 1024; ++p) s += xp[(size_t)p << 10];
    unsafeAtomicAdd(&musum[d], (double)s);
  }
  gbarO(bcnt, bgen);

  if (b < KMAX) {
    double* w = (double*)smem;
    const int k = b;
    if (k == 0) {
      double ss = 0.0;
      #pragma unroll
      for (int r = 0; r < 4; ++r) {
        int d = (r << 8) + tid;
        float m = (float)(musum[d] * (1.0 / 65536.0));
        mu[d] = m;
        ss += (double)m * (double)m;
      }
      #pragma unroll
      for (int mk = 1; mk < 64; mk <<= 1) ss += __shfl_xor(ss, mk);
      if (lane == 0) w[wv] = ss;
      __syncthreads();
      if (tid == 0) m2f[0] = (float)(w[0] + w[1] + w[2] + w[3]);
    } else {
      #pragma unroll
      for (int r = 0; r < 4; ++r) mu[(k << 10) + (r << 8) + tid] = 0.f;
      if (tid == 0) m2f[k] = 0.f;
    }
  }
  gbarO(bcnt, bgen);

  for (int t = 0; t < 50; ++t) {
    const int dn = *(volatile int*)&sc->done;
    if (dn) break;
    const int K = *(volatile int*)&sc->K;
    const int Kc = (K < KMAX - 1) ? K : (KMAX - 1);
    const int slot = t & 1;

    {
      const int gneed = (K + 7) >> 3;
      if (gneed <= 1)      phaseAO<1>(X, mu, x2, z, m2f, sc, smem, b, tid, K, Kc, slot);
      else if (gneed <= 2) phaseAO<2>(X, mu, x2, z, m2f, sc, smem, b, tid, K, Kc, slot);
      else if (gneed <= 4) phaseAO<4>(X, mu, x2, z, m2f, sc, smem, b, tid, K, Kc, slot);
      else                 phaseAO<8>(X, mu, x2, z, m2f, sc, smem, b, tid, K, Kc, slot);
    }
    gbarO(bcnt, bgen);

    {
      float (*accS)[256] = (float (*)[256])(void*)smem;
      const int dcb = b & 3, nb = b >> 2;
      const int p0 = nb << 10;
      #pragma unroll
      for (int k = 0; k < KMAX; ++k) accS[k][tid] = 0.f;
      __syncthreads();
      const float* xp = X + ((size_t)p0 << 10) + (dcb << 8) + tid;
      const int* zp = z + p0;
      for (int p = 0; p < 1024; ++p)
        accS[zp[p]][tid] += xp[(size_t)p << 10];
      __syncthreads();
      for (int k = 0; k < KMAX; ++k)
        if (sc->counts[slot][k] > 0)
          unsafeAtomicAdd(&sums[(k << 10) + (dcb << 8) + tid], (double)accS[k][tid]);
    }
    gbarO(bcnt, bgen);

    if (b < KMAX) {
      double* w = (double*)smem;
      const int k = b;
      const int c = sc->counts[slot][k];
      const double inv = (c > 0) ? 1.0 / (double)c : 0.0;
      double ss = 0.0;
      #pragma unroll
      for (int r = 0; r < 4; ++r) {
        int d = (r << 8) + tid;
        float m = mu[(k << 10) + d];
        if (c > 0) m = (float)(sums[(k << 10) + d] * inv);
        mu[(k << 10) + d] = m;
        sums[(k << 10) + d] = 0.0;
        ss += (double)m * (double)m;
      }
      #pragma unroll
      for (int mk = 1; mk < 64; mk <<= 1) ss += __shfl_xor(ss, mk);
      if (lane == 0) w[wv] = ss;
      __syncthreads();
      float m2k = 0.f;
      if (tid == 0) {
        m2k = (float)(w[0] + w[1] + w[2] + w[3]);
        m2f[k] = m2k;
      }
      if (k == Kc) {
        if (tid < 64) sc->counts[slot ^ 1][tid] = 0;
        if (tid == 0) {
          sc->s_all[slot ^ 1] = 0.0; sc->s_far[slot ^ 1] = 0.0;
          sc->sx2far[slot ^ 1] = 0.0; sc->farcnt[slot ^ 1] = 0;
          int farc = sc->farcnt[slot];
          int create = (farc > 0 && K < KMAX) ? 1 : 0;
          int Knew = K + create;
          double obj;
          if (create)
            obj = (sc->s_all[slot] - sc->s_far[slot]) +
                  (sc->sx2far[slot] - (double)farc * (double)m2k);
          else
            obj = sc->s_all[slot];
          obj += 1000.0 * (double)Knew;
          int conv = (sc->it > 0) && (fabs(obj - sc->prev_obj) < 1e-3 * obj);
          sc->done = conv;
          sc->prev_obj = obj;
          sc->K = Knew;
          sc->it = sc->it + 1;
        }
      }
    }
    gbarO(bcnt, bgen);
  }
}

// ---------------- host ----------------

extern "C" void kernel_launch(void* const* d_in, const int* in_sizes, int n_in,
                              void* d_out, int out_size, void* d_ws, size_t ws_size,
                              hipStream_t stream) {
  const float* X = (const float*)d_in[0];
  float* mu = (float*)d_out;                   // 64 x 1024 fp32 output
  char* ws = (char*)d_ws;
  float*  x2    = (float*)(ws + 0);            // 256 KB
  int*    z     = (int*)(ws + 262144);         // 256 KB
  double* sums  = (double*)(ws + 524288);      // 512 KB
  double* musum = (double*)(ws + 1048576);     // 8 KB
  float*  m2f   = (float*)(ws + 1056768);      // 256 B
  Scal*   sc    = (Scal*)(ws + 1057024);       // ~600 B
  int*    bar   = (int*)(ws + 1058048);        // 8 KB (tree barrier)
  float*  XT    = (float*)(ws + (size_t)(2u << 20));  // 268.4 MB transposed X

  const size_t need = (size_t)(2u << 20) + (size_t)DDIM * NPTS * sizeof(float);

  kInit<<<1, 1024, 0, stream>>>(bar);
  if (ws_size >= need)
    kMainP<<<GRIDP, 256, 0, stream>>>(X, mu, x2, z, sums, musum, m2f, sc, bar, XT);
  else
    kMainOld<<<GRID, 256, 0, stream>>>(X, mu, x2, z, sums, musum, m2f, sc, bar);
}

// Round 5
// 1062.503 us; speedup vs baseline: 1.3816x; 1.3816x over previous
//
#include <hip/hip_runtime.h>
#include <math.h>

// DP-means on MI355X — single persistent kernel, device-wide tree barrier.
// Round 5: back to the verified round-2 skeleton (896 us), three serial cuts:
//   (1) Phase D: wave-uniform run-length register cache kills the
//       same-address LDS RMW chain (z mostly equal in early iters).
//   (2) Init: x2 + musum fused into the XT transpose pass (removes two
//       268 MB passes + one grid barrier).
//   (3) Tree barrier: drop explicit __threadfence(); the acq_rel/acquire
//       agent-scope atomics already carry the L2 wb/inv semantics.
// Phase A / phase E / LDS layouts byte-identical to round 2.

#define NPTS   65536
#define DDIM   1024
#define KMAX   64
#define GRID   256
#define LAMBDA_F 1000.0f
#define INF_F  1e30f

struct Scal {
  int K, it, done, _p;
  double prev_obj;
  double s_all[2], s_far[2], sx2far[2];
  int farcnt[2];
  int counts[2][64];
};

// ---------------- barriers ----------------

// fallback path barrier (legacy, with fences)
__device__ __forceinline__ void gbarO(int* cnt, int* gen) {
  __syncthreads();
  if (threadIdx.x == 0) {
    __threadfence();
    int g = __hip_atomic_load(gen, __ATOMIC_RELAXED, __HIP_MEMORY_SCOPE_AGENT);
    int a = __hip_atomic_fetch_add(cnt, 1, __ATOMIC_ACQ_REL, __HIP_MEMORY_SCOPE_AGENT);
    if (a == GRID - 1) {
      __hip_atomic_store(cnt, 0, __ATOMIC_RELAXED, __HIP_MEMORY_SCOPE_AGENT);
      __hip_atomic_store(gen, g + 1, __ATOMIC_RELEASE, __HIP_MEMORY_SCOPE_AGENT);
    } else {
      while (__hip_atomic_load(gen, __ATOMIC_ACQUIRE, __HIP_MEMORY_SCOPE_AGENT) == g)
        __builtin_amdgcn_s_sleep(2);
    }
    __threadfence();
  }
  __syncthreads();
}

// tree barrier, monotonic counters, NO explicit fences: release/acquire
// chain (leaf acq_rel -> root acq_rel -> gen release; waiter acquire)
// transitively publishes every block's pre-barrier writes.
// leaf[i]=bar[i*32] (i<32, 8 blocks each), root=bar[1024], gen=bar[1056].
__device__ __forceinline__ void gbarT(int* bar, int b, int r) {
  __syncthreads();
  if (threadIdx.x == 0) {
    int* leaf = bar + ((b >> 3) << 5);
    int v = __hip_atomic_fetch_add(leaf, 1, __ATOMIC_ACQ_REL, __HIP_MEMORY_SCOPE_AGENT);
    if (v == (r << 3) - 1) {
      int w = __hip_atomic_fetch_add(bar + 1024, 1, __ATOMIC_ACQ_REL, __HIP_MEMORY_SCOPE_AGENT);
      if (w == (r << 5) - 1)
        __hip_atomic_store(bar + 1056, r, __ATOMIC_RELEASE, __HIP_MEMORY_SCOPE_AGENT);
    }
    while (__hip_atomic_load(bar + 1056, __ATOMIC_ACQUIRE, __HIP_MEMORY_SCOPE_AGENT) < r)
      __builtin_amdgcn_s_sleep(2);
  }
  __syncthreads();
}

__global__ void kInit(int* bar) { bar[threadIdx.x] = 0; bar[1024 + threadIdx.x] = 0; }

// ============================================================
// Phase A — byte-identical to round 2 (896 us verified).
// ============================================================
template <int GP>
__device__ __forceinline__ void phaseAT(
    const float* __restrict__ XT, const float* __restrict__ mu,
    const float* __restrict__ x2, int* __restrict__ z,
    const float* __restrict__ m2f, Scal* sc, char* smem,
    int b, int tid, int K, int Kc, int slot) {
  constexpr int LSTR = 34;
  constexpr int LGP = (GP == 1) ? 0 : (GP == 2) ? 1 : (GP == 4) ? 2 : 3;
  constexpr int MUTOT = GP * 128;
  constexpr int MURND = (MUTOT + 255) / 256;

  float*  lX   = (float*)smem;             // 34816 B
  float*  lMu  = (float*)(smem + 34816);   //  8704 B
  double* wred = (double*)(smem + 43520);
  int*    wfc  = (int*)(smem + 43616);
  int*    lcnt = (int*)(smem + 43648);
  float*  rdm  = (float*)smem;             // reuse after GEMM
  int*    rkm  = (int*)(smem + 9216);

  const int lane = tid & 63, wv = tid >> 6;
  const int pg = tid & 31, tg = tid >> 5;
  const int kg = tg & (GP - 1);
  const int sub = tg >> LGP;
  const int pbase = b << 8;
  const int p0loc = sub * (GP << 5);
  const int jrow = tid >> 3, q = tid & 7;   // staging role: dim-row, point-quad

  if (tid < KMAX) lcnt[tid] = 0;

  float acc[GP][8];
  #pragma unroll
  for (int i = 0; i < GP; ++i)
    #pragma unroll
    for (int j = 0; j < 8; ++j) acc[i][j] = 0.f;

  float4 xr4[8];
  float2 mr[MURND];

  // prologue: prefetch chunk 0
  #pragma unroll
  for (int i = 0; i < 8; ++i)
    xr4[i] = *(const float4*)&XT[(size_t)jrow * NPTS + pbase + (i << 5) + (q << 2)];
  #pragma unroll
  for (int r = 0; r < MURND; ++r) {
    int idx = (r << 8) + tid;
    if (idx < MUTOT) {
      int k = idx >> 4, c2 = (idx & 15) << 1;
      mr[r] = *(const float2*)&mu[(k << 10) + c2];
    }
  }

  for (int dc = 0; dc < DDIM; dc += 32) {
    __syncthreads();
    #pragma unroll
    for (int i = 0; i < 8; ++i) {
      const int p = (i << 5) + (q << 2);
      lX[(p + 0) * LSTR + jrow] = xr4[i].x;
      lX[(p + 1) * LSTR + jrow] = xr4[i].y;
      lX[(p + 2) * LSTR + jrow] = xr4[i].z;
      lX[(p + 3) * LSTR + jrow] = xr4[i].w;
    }
    #pragma unroll
    for (int r = 0; r < MURND; ++r) {
      int idx = (r << 8) + tid;
      if (idx < MUTOT) {
        int k = idx >> 4, c2 = (idx & 15) << 1;
        *(float2*)&lMu[k * LSTR + c2] = mr[r];
      }
    }
    __syncthreads();
    // T14: issue next chunk's loads; latency hides under compute below.
    const int dcn = dc + 32;
    if (dcn < DDIM) {
      #pragma unroll
      for (int i = 0; i < 8; ++i)
        xr4[i] = *(const float4*)&XT[(size_t)(dcn + jrow) * NPTS + pbase + (i << 5) + (q << 2)];
      #pragma unroll
      for (int r = 0; r < MURND; ++r) {
        int idx = (r << 8) + tid;
        if (idx < MUTOT) {
          int k = idx >> 4, c2 = (idx & 15) << 1;
          mr[r] = *(const float2*)&mu[(k << 10) + dcn + c2];
        }
      }
    }
    for (int d2 = 0; d2 < 16; ++d2) {
      float2 ma[8], xa[GP];
      #pragma unroll
      for (int j = 0; j < 8; ++j)
        ma[j] = *(const float2*)&lMu[((kg << 3) + j) * LSTR + (d2 << 1)];
      #pragma unroll
      for (int i = 0; i < GP; ++i)
        xa[i] = *(const float2*)&lX[(p0loc + (i << 5) + pg) * LSTR + (d2 << 1)];
      #pragma unroll
      for (int i = 0; i < GP; ++i)
        #pragma unroll
        for (int j = 0; j < 8; ++j)
          acc[i][j] = fmaf(xa[i].y, ma[j].y, fmaf(xa[i].x, ma[j].x, acc[i][j]));
    }
  }
  __syncthreads();

  float m2v[8];
  #pragma unroll
  for (int j = 0; j < 8; ++j) m2v[j] = m2f[(kg << 3) + j];
  float x2v[GP];
  #pragma unroll
  for (int i = 0; i < GP; ++i) x2v[i] = x2[pbase + p0loc + (i << 5) + pg];

  #pragma unroll
  for (int i = 0; i < GP; ++i) {
    float bd2 = INF_F; int bk2 = KMAX;
    #pragma unroll
    for (int j = 0; j < 8; ++j) {
      int k = (kg << 3) + j;
      if (k < K) {
        float dist = x2v[i] - 2.0f * acc[i][j] + m2v[j];
        if (dist < bd2) { bd2 = dist; bk2 = k; }
      }
    }
    const int pl = p0loc + (i << 5) + pg;
    rdm[pl * 9 + kg] = bd2;
    rkm[pl * 9 + kg] = bk2;
  }
  __syncthreads();

  float bd = INF_F; int bk = KMAX;
  #pragma unroll
  for (int g = 0; g < GP; ++g) {
    float dv = rdm[tid * 9 + g]; int kv = rkm[tid * 9 + g];
    if (dv < bd || (dv == bd && kv < bk)) { bd = dv; bk = kv; }
  }

  const bool far = bd > LAMBDA_F;
  const int zf = (far && (K < KMAX)) ? Kc : bk;
  z[pbase + tid] = zf;
  atomicAdd(&lcnt[zf], 1);

  const float x2p = x2[pbase + tid];
  double a = (double)bd;
  double f = far ? (double)bd : 0.0;
  double xf = far ? (double)x2p : 0.0;
  unsigned long long bal = __ballot(far);
  int fc = __popcll(bal);
  #pragma unroll
  for (int m = 1; m < 64; m <<= 1) {
    a += __shfl_xor(a, m); f += __shfl_xor(f, m); xf += __shfl_xor(xf, m);
  }
  if (lane == 0) { wred[wv] = a; wred[4 + wv] = f; wred[8 + wv] = xf; wfc[wv] = fc; }
  __syncthreads();
  if (tid == 0) {
    unsafeAtomicAdd(&sc->s_all[slot],  wred[0] + wred[1] + wred[2] + wred[3]);
    unsafeAtomicAdd(&sc->s_far[slot],  wred[4] + wred[5] + wred[6] + wred[7]);
    unsafeAtomicAdd(&sc->sx2far[slot], wred[8] + wred[9] + wred[10] + wred[11]);
    atomicAdd(&sc->farcnt[slot], wfc[0] + wfc[1] + wfc[2] + wfc[3]);
  }
  if (tid < KMAX) {
    int c = lcnt[tid];
    if (c > 0) atomicAdd(&sc->counts[slot][tid], c);
  }
}

__global__ __launch_bounds__(256, 1) void kMainT(
    const float* __restrict__ X, float* __restrict__ mu,
    float* __restrict__ x2, int* __restrict__ z,
    double* __restrict__ sums, double* __restrict__ musum,
    float* __restrict__ m2f, Scal* sc, int* bar, float* __restrict__ XT) {
  __shared__ __align__(16) char smem[65536];
  const int tid = threadIdx.x;
  const int b = blockIdx.x;
  const int lane = tid & 63, wv = tid >> 6;
  int rnd = 0;

  // ---- I0: zero persistent state ----
  sums[(b << 8) + tid] = 0.0;
  if (b == 0) {
    if (tid < 64) { sc->counts[0][tid] = 0; sc->counts[1][tid] = 0; }
    if (tid == 0) {
      sc->K = 1; sc->it = 0; sc->done = 0; sc->prev_obj = 0.0;
      for (int s2 = 0; s2 < 2; ++s2) {
        sc->s_all[s2] = 0.0; sc->s_far[s2] = 0.0; sc->sx2far[s2] = 0.0; sc->farcnt[s2] = 0;
      }
    }
  }
  if (b == 1) {
    musum[tid] = 0.0; musum[256 + tid] = 0.0;
    musum[512 + tid] = 0.0; musum[768 + tid] = 0.0;
  }
  gbarT(bar, b, ++rnd);

  // ---- I1 (FUSED): one pass over X builds XT + x2 + musum ----
  {
    const int pbase = b << 8;
    const int jrow = tid >> 3, q = tid & 7;
    float* lX = (float*)smem;  // [256][34]
    float x2acc = 0.f;
    for (int dc = 0; dc < DDIM; dc += 32) {
      __syncthreads();
      #pragma unroll
      for (int r = 0; r < 16; ++r) {
        int idx = (r << 8) + tid;
        int p = idx >> 4, c2 = (idx & 15) << 1;
        *(float2*)&lX[p * 34 + c2] =
            *(const float2*)&X[((size_t)(pbase + p) << 10) + dc + c2];
      }
      __syncthreads();
      // transpose-write to XT + musum partial (thread holds 32 pts of dim dc+jrow)
      float ms = 0.f;
      #pragma unroll
      for (int i = 0; i < 8; ++i) {
        const int p = (i << 5) + (q << 2);
        float4 v;
        v.x = lX[(p + 0) * 34 + jrow];
        v.y = lX[(p + 1) * 34 + jrow];
        v.z = lX[(p + 2) * 34 + jrow];
        v.w = lX[(p + 3) * 34 + jrow];
        *(float4*)&XT[(size_t)(dc + jrow) * NPTS + pbase + p] = v;
        ms += v.x; ms += v.y; ms += v.z; ms += v.w;
      }
      #pragma unroll
      for (int m = 1; m < 8; m <<= 1) ms += __shfl_xor(ms, m);
      if (q == 0) unsafeAtomicAdd(&musum[dc + jrow], (double)ms);
      // x2 partial: thread owns point tid, 32 dims of this chunk (2-way free)
      #pragma unroll
      for (int c = 0; c < 32; ++c) {
        float v = lX[tid * 34 + c];
        x2acc = fmaf(v, v, x2acc);
      }
    }
    x2[pbase + tid] = x2acc;
  }
  gbarT(bar, b, ++rnd);

  // ---- I2: mu[0]=mean, mu[k>0]=0, m2 ----
  if (b < KMAX) {
    double* w = (double*)smem;
    const int k = b;
    if (k == 0) {
      double ss = 0.0;
      #pragma unroll
      for (int r = 0; r < 4; ++r) {
        int d = (r << 8) + tid;
        float m = (float)(musum[d] * (1.0 / 65536.0));
        mu[d] = m;
        ss += (double)m * (double)m;
      }
      #pragma unroll
      for (int mk = 1; mk < 64; mk <<= 1) ss += __shfl_xor(ss, mk);
      if (lane == 0) w[wv] = ss;
      __syncthreads();
      if (tid == 0) m2f[0] = (float)(w[0] + w[1] + w[2] + w[3]);
    } else {
      #pragma unroll
      for (int r = 0; r < 4; ++r) mu[(k << 10) + (r << 8) + tid] = 0.f;
      if (tid == 0) m2f[k] = 0.f;
    }
  }
  gbarT(bar, b, ++rnd);

  // ---- main loop ----
  for (int t = 0; t < 50; ++t) {
    const int dn = *(volatile int*)&sc->done;
    if (dn) break;
    const int K = *(volatile int*)&sc->K;
    const int Kc = (K < KMAX - 1) ? K : (KMAX - 1);
    const int slot = t & 1;

    {
      const int gneed = (K + 7) >> 3;
      if (gneed <= 1)      phaseAT<1>(XT, mu, x2, z, m2f, sc, smem, b, tid, K, Kc, slot);
      else if (gneed <= 2) phaseAT<2>(XT, mu, x2, z, m2f, sc, smem, b, tid, K, Kc, slot);
      else if (gneed <= 4) phaseAT<4>(XT, mu, x2, z, m2f, sc, smem, b, tid, K, Kc, slot);
      else                 phaseAT<8>(XT, mu, x2, z, m2f, sc, smem, b, tid, K, Kc, slot);
    }
    gbarT(bar, b, ++rnd);

    // ---- Phase D: segment sums with run-length register cache.
    // z is identical across the wave -> branch is wave-uniform. Long
    // same-z runs (early iters) become a fadd register chain instead of
    // a same-address LDS RMW chain. Adds per (k,tid) stay in ascending
    // point order (association within runs differs; tolerance-level). ----
    {
      float (*accS)[256] = (float (*)[256])(void*)smem;  // 64 KB
      const int dcb = b & 3, nb = b >> 2;
      const int p0 = nb << 10;
      #pragma unroll
      for (int k = 0; k < KMAX; ++k) accS[k][tid] = 0.f;
      __syncthreads();
      const float* xrow = XT + (size_t)((dcb << 8) + tid) * NPTS + p0;
      const int* zp = z + p0;
      int kcur = zp[0];
      float acc = 0.f;
      #pragma unroll 4
      for (int p4 = 0; p4 < 256; ++p4) {
        float4 xc = *(const float4*)&xrow[p4 << 2];
        int4  zc = *(const int4*)&zp[p4 << 2];
        if (zc.x != kcur) { accS[kcur][tid] += acc; kcur = zc.x; acc = xc.x; } else acc += xc.x;
        if (zc.y != kcur) { accS[kcur][tid] += acc; kcur = zc.y; acc = xc.y; } else acc += xc.y;
        if (zc.z != kcur) { accS[kcur][tid] += acc; kcur = zc.z; acc = xc.z; } else acc += xc.z;
        if (zc.w != kcur) { accS[kcur][tid] += acc; kcur = zc.w; acc = xc.w; } else acc += xc.w;
      }
      accS[kcur][tid] += acc;
      __syncthreads();
      for (int k = 0; k < KMAX; ++k)
        if (sc->counts[slot][k] > 0)
          unsafeAtomicAdd(&sums[(k << 10) + (dcb << 8) + tid], (double)accS[k][tid]);
    }
    gbarT(bar, b, ++rnd);

    // ---- Phase E: centroid means + m2; block Kc does epilogue ----
    if (b < KMAX) {
      double* w = (double*)smem;
      const int k = b;
      const int c = sc->counts[slot][k];
      const double inv = (c > 0) ? 1.0 / (double)c : 0.0;
      double ss = 0.0;
      #pragma unroll
      for (int r = 0; r < 4; ++r) {
        int d = (r << 8) + tid;
        float m = mu[(k << 10) + d];
        if (c > 0) m = (float)(sums[(k << 10) + d] * inv);
        mu[(k << 10) + d] = m;
        sums[(k << 10) + d] = 0.0;          // reset for next iteration
        ss += (double)m * (double)m;
      }
      #pragma unroll
      for (int mk = 1; mk < 64; mk <<= 1) ss += __shfl_xor(ss, mk);
      if (lane == 0) w[wv] = ss;
      __syncthreads();
      float m2k = 0.f;
      if (tid == 0) {
        m2k = (float)(w[0] + w[1] + w[2] + w[3]);
        m2f[k] = m2k;
      }
      if (k == Kc) {
        if (tid < 64) sc->counts[slot ^ 1][tid] = 0;
        if (tid == 0) {
          sc->s_all[slot ^ 1] = 0.0; sc->s_far[slot ^ 1] = 0.0;
          sc->sx2far[slot ^ 1] = 0.0; sc->farcnt[slot ^ 1] = 0;
          int farc = sc->farcnt[slot];
          int create = (farc > 0 && K < KMAX) ? 1 : 0;
          int Knew = K + create;
          double obj;
          if (create)
            obj = (sc->s_all[slot] - sc->s_far[slot]) +
                  (sc->sx2far[slot] - (double)farc * (double)m2k);
          else
            obj = sc->s_all[slot];
          obj += 1000.0 * (double)Knew;
          int conv = (sc->it > 0) && (fabs(obj - sc->prev_obj) < 1e-3 * obj);
          sc->done = conv;
          sc->prev_obj = obj;
          sc->K = Knew;
          sc->it = sc->it + 1;
        }
      }
    }
    gbarT(bar, b, ++rnd);
  }
}

// ============================================================
// FALLBACK: round-1 kernel (used only if ws can't hold XT)
// ============================================================
template <int GP>
__device__ __forceinline__ void phaseAO(
    const float* __restrict__ X, const float* __restrict__ mu,
    const float* __restrict__ x2, int* __restrict__ z,
    const float* __restrict__ m2f, Scal* sc, char* smem,
    int b, int tid, int K, int Kc, int slot) {
  constexpr int LSTR = 34;
  constexpr int LGP = (GP == 1) ? 0 : (GP == 2) ? 1 : (GP == 4) ? 2 : 3;
  constexpr int MUTOT = GP * 128;
  constexpr int MURND = (MUTOT + 255) / 256;

  float*  lX   = (float*)smem;
  float*  lMu  = (float*)(smem + 34816);
  double* wred = (double*)(smem + 43520);
  int*    wfc  = (int*)(smem + 43616);
  int*    lcnt = (int*)(smem + 43648);
  float*  rdm  = (float*)smem;
  int*    rkm  = (int*)(smem + 9216);

  const int lane = tid & 63, wv = tid >> 6;
  const int pg = tid & 31, tg = tid >> 5;
  const int kg = tg & (GP - 1);
  const int sub = tg >> LGP;
  const int pbase = b << 8;
  const int p0loc = sub * (GP << 5);

  if (tid < KMAX) lcnt[tid] = 0;

  float acc[GP][8];
  #pragma unroll
  for (int i = 0; i < GP; ++i)
    #pragma unroll
    for (int j = 0; j < 8; ++j) acc[i][j] = 0.f;

  float2 xr[16];
  float2 mr[MURND];

  #pragma unroll
  for (int r = 0; r < 16; ++r) {
    int idx = (r << 8) + tid;
    int p = idx >> 4, c2 = (idx & 15) << 1;
    xr[r] = *(const float2*)&X[((size_t)(pbase + p) << 10) + c2];
  }
  #pragma unroll
  for (int r = 0; r < MURND; ++r) {
    int idx = (r << 8) + tid;
    if (idx < MUTOT) {
      int k = idx >> 4, c2 = (idx & 15) << 1;
      mr[r] = *(const float2*)&mu[(k << 10) + c2];
    }
  }

  for (int dc = 0; dc < DDIM; dc += 32) {
    __syncthreads();
    #pragma unroll
    for (int r = 0; r < 16; ++r) {
      int idx = (r << 8) + tid;
      int p = idx >> 4, c2 = (idx & 15) << 1;
      *(float2*)&lX[p * LSTR + c2] = xr[r];
    }
    #pragma unroll
    for (int r = 0; r < MURND; ++r) {
      int idx = (r << 8) + tid;
      if (idx < MUTOT) {
        int k = idx >> 4, c2 = (idx & 15) << 1;
        *(float2*)&lMu[k * LSTR + c2] = mr[r];
      }
    }
    __syncthreads();
    const int dcn = dc + 32;
    if (dcn < DDIM) {
      #pragma unroll
      for (int r = 0; r < 16; ++r) {
        int idx = (r << 8) + tid;
        int p = idx >> 4, c2 = (idx & 15) << 1;
        xr[r] = *(const float2*)&X[((size_t)(pbase + p) << 10) + dcn + c2];
      }
      #pragma unroll
      for (int r = 0; r < MURND; ++r) {
        int idx = (r << 8) + tid;
        if (idx < MUTOT) {
          int k = idx >> 4, c2 = (idx & 15) << 1;
          mr[r] = *(const float2*)&mu[(k << 10) + dcn + c2];
        }
      }
    }
    for (int d2 = 0; d2 < 16; ++d2) {
      float2 ma[8], xa[GP];
      #pragma unroll
      for (int j = 0; j < 8; ++j)
        ma[j] = *(const float2*)&lMu[((kg << 3) + j) * LSTR + (d2 << 1)];
      #pragma unroll
      for (int i = 0; i < GP; ++i)
        xa[i] = *(const float2*)&lX[(p0loc + (i << 5) + pg) * LSTR + (d2 << 1)];
      #pragma unroll
      for (int i = 0; i < GP; ++i)
        #pragma unroll
        for (int j = 0; j < 8; ++j)
          acc[i][j] = fmaf(xa[i].y, ma[j].y, fmaf(xa[i].x, ma[j].x, acc[i][j]));
    }
  }
  __syncthreads();

  float m2v[8];
  #pragma unroll
  for (int j = 0; j < 8; ++j) m2v[j] = m2f[(kg << 3) + j];
  float x2v[GP];
  #pragma unroll
  for (int i = 0; i < GP; ++i) x2v[i] = x2[pbase + p0loc + (i << 5) + pg];

  #pragma unroll
  for (int i = 0; i < GP; ++i) {
    float bd2 = INF_F; int bk2 = KMAX;
    #pragma unroll
    for (int j = 0; j < 8; ++j) {
      int k = (kg << 3) + j;
      if (k < K) {
        float dist = x2v[i] - 2.0f * acc[i][j] + m2v[j];
        if (dist < bd2) { bd2 = dist; bk2 = k; }
      }
    }
    const int pl = p0loc + (i << 5) + pg;
    rdm[pl * 9 + kg] = bd2;
    rkm[pl * 9 + kg] = bk2;
  }
  __syncthreads();

  float bd = INF_F; int bk = KMAX;
  #pragma unroll
  for (int g = 0; g < GP; ++g) {
    float dv = rdm[tid * 9 + g]; int kv = rkm[tid * 9 + g];
    if (dv < bd || (dv == bd && kv < bk)) { bd = dv; bk = kv; }
  }

  const bool far = bd > LAMBDA_F;
  const int zf = (far && (K < KMAX)) ? Kc : bk;
  z[pbase + tid] = zf;
  atomicAdd(&lcnt[zf], 1);

  const float x2p = x2[pbase + tid];
  double a = (double)bd;
  double f = far ? (double)bd : 0.0;
  double xf = far ? (double)x2p : 0.0;
  unsigned long long bal = __ballot(far);
  int fc = __popcll(bal);
  #pragma unroll
  for (int m = 1; m < 64; m <<= 1) {
    a += __shfl_xor(a, m); f += __shfl_xor(f, m); xf += __shfl_xor(xf, m);
  }
  if (lane == 0) { wred[wv] = a; wred[4 + wv] = f; wred[8 + wv] = xf; wfc[wv] = fc; }
  __syncthreads();
  if (tid == 0) {
    unsafeAtomicAdd(&sc->s_all[slot],  wred[0] + wred[1] + wred[2] + wred[3]);
    unsafeAtomicAdd(&sc->s_far[slot],  wred[4] + wred[5] + wred[6] + wred[7]);
    unsafeAtomicAdd(&sc->sx2far[slot], wred[8] + wred[9] + wred[10] + wred[11]);
    atomicAdd(&sc->farcnt[slot], wfc[0] + wfc[1] + wfc[2] + wfc[3]);
  }
  if (tid < KMAX) {
    int c = lcnt[tid];
    if (c > 0) atomicAdd(&sc->counts[slot][tid], c);
  }
}

__global__ __launch_bounds__(256, 1) void kMainOld(
    const float* __restrict__ X, float* __restrict__ mu,
    float* __restrict__ x2, int* __restrict__ z,
    double* __restrict__ sums, double* __restrict__ musum,
    float* __restrict__ m2f, Scal* sc, int* bar) {
  __shared__ __align__(16) char smem[65536];
  const int tid = threadIdx.x;
  const int b = blockIdx.x;
  const int lane = tid & 63, wv = tid >> 6;
  int* bcnt = bar;
  int* bgen = bar + 32;

  sums[(b << 8) + tid] = 0.0;
  if (b == 0) {
    if (tid < 64) { sc->counts[0][tid] = 0; sc->counts[1][tid] = 0; }
    if (tid == 0) {
      sc->K = 1; sc->it = 0; sc->done = 0; sc->prev_obj = 0.0;
      for (int s2 = 0; s2 < 2; ++s2) {
        sc->s_all[s2] = 0.0; sc->s_far[s2] = 0.0; sc->sx2far[s2] = 0.0; sc->farcnt[s2] = 0;
      }
    }
  }
  if (b == 1) {
    musum[tid] = 0.0; musum[256 + tid] = 0.0;
    musum[512 + tid] = 0.0; musum[768 + tid] = 0.0;
  }
  gbarO(bcnt, bgen);

  {
    const int pbase = b << 8;
    for (int i = 0; i < 64; ++i) {
      const int p = pbase + (i << 2) + wv;
      const float* row = X + ((size_t)p << 10);
      float s = 0.f;
      #pragma unroll
      for (int c = 0; c < 4; ++c) {
        float4 v = *(const float4*)&row[(c << 8) + (lane << 2)];
        s += v.x * v.x + v.y * v.y + v.z * v.z + v.w * v.w;
      }
      #pragma unroll
      for (int m = 1; m < 64; m <<= 1) s += __shfl_xor(s, m);
      if (lane == 0) x2[p] = s;
    }
    const int dcb = b & 3, nb = b >> 2;
    const int d = (dcb << 8) + tid;
    const float* xp = X + ((size_t)nb << 20) + d;
    float s = 0.f;
    for (int p = 0; p < 1024; ++p) s += xp[(size_t)p << 10];
    unsafeAtomicAdd(&musum[d], (double)s);
  }
  gbarO(bcnt, bgen);

  if (b < KMAX) {
    double* w = (double*)smem;
    const int k = b;
    if (k == 0) {
      double ss = 0.0;
      #pragma unroll
      for (int r = 0; r < 4; ++r) {
        int d = (r << 8) + tid;
        float m = (float)(musum[d] * (1.0 / 65536.0));
        mu[d] = m;
        ss += (double)m * (double)m;
      }
      #pragma unroll
      for (int mk = 1; mk < 64; mk <<= 1) ss += __shfl_xor(ss, mk);
      if (lane == 0) w[wv] = ss;
      __syncthreads();
      if (tid == 0) m2f[0] = (float)(w[0] + w[1] + w[2] + w[3]);
    } else {
      #pragma unroll
      for (int r = 0; r < 4; ++r) mu[(k << 10) + (r << 8) + tid] = 0.f;
      if (tid == 0) m2f[k] = 0.f;
    }
  }
  gbarO(bcnt, bgen);

  for (int t = 0; t < 50; ++t) {
    const int dn = *(volatile int*)&sc->done;
    if (dn) break;
    const int K = *(volatile int*)&sc->K;
    const int Kc = (K < KMAX - 1) ? K : (KMAX - 1);
    const int slot = t & 1;

    {
      const int gneed = (K + 7) >> 3;
      if (gneed <= 1)      phaseAO<1>(X, mu, x2, z, m2f, sc, smem, b, tid, K, Kc, slot);
      else if (gneed <= 2) phaseAO<2>(X, mu, x2, z, m2f, sc, smem, b, tid, K, Kc, slot);
      else if (gneed <= 4) phaseAO<4>(X, mu, x2, z, m2f, sc, smem, b, tid, K, Kc, slot);
      else                 phaseAO<8>(X, mu, x2, z, m2f, sc, smem, b, tid, K, Kc, slot);
    }
    gbarO(bcnt, bgen);

    {
      float (*accS)[256] = (float (*)[256])(void*)smem;
      const int dcb = b & 3, nb = b >> 2;
      const int p0 = nb << 10;
      #pragma unroll
      for (int k = 0; k < KMAX; ++k) accS[k][tid] = 0.f;
      __syncthreads();
      const float* xp = X + ((size_t)p0 << 10) + (dcb << 8) + tid;
      const int* zp = z + p0;
      for (int p = 0; p < 1024; ++p)
        accS[zp[p]][tid] += xp[(size_t)p << 10];
      __syncthreads();
      for (int k = 0; k < KMAX; ++k)
        if (sc->counts[slot][k] > 0)
          unsafeAtomicAdd(&sums[(k << 10) + (dcb << 8) + tid], (double)accS[k][tid]);
    }
    gbarO(bcnt, bgen);

    if (b < KMAX) {
      double* w = (double*)smem;
      const int k = b;
      const int c = sc->counts[slot][k];
      const double inv = (c > 0) ? 1.0 / (double)c : 0.0;
      double ss = 0.0;
      #pragma unroll
      for (int r = 0; r < 4; ++r) {
        int d = (r << 8) + tid;
        float m = mu[(k << 10) + d];
        if (c > 0) m = (float)(sums[(k << 10) + d] * inv);
        mu[(k << 10) + d] = m;
        sums[(k << 10) + d] = 0.0;
        ss += (double)m * (double)m;
      }
      #pragma unroll
      for (int mk = 1; mk < 64; mk <<= 1) ss += __shfl_xor(ss, mk);
      if (lane == 0) w[wv] = ss;
      __syncthreads();
      float m2k = 0.f;
      if (tid == 0) {
        m2k = (float)(w[0] + w[1] + w[2] + w[3]);
        m2f[k] = m2k;
      }
      if (k == Kc) {
        if (tid < 64) sc->counts[slot ^ 1][tid] = 0;
        if (tid == 0) {
          sc->s_all[slot ^ 1] = 0.0; sc->s_far[slot ^ 1] = 0.0;
          sc->sx2far[slot ^ 1] = 0.0; sc->farcnt[slot ^ 1] = 0;
          int farc = sc->farcnt[slot];
          int create = (farc > 0 && K < KMAX) ? 1 : 0;
          int Knew = K + create;
          double obj;
          if (create)
            obj = (sc->s_all[slot] - sc->s_far[slot]) +
                  (sc->sx2far[slot] - (double)farc * (double)m2k);
          else
            obj = sc->s_all[slot];
          obj += 1000.0 * (double)Knew;
          int conv = (sc->it > 0) && (fabs(obj - sc->prev_obj) < 1e-3 * obj);
          sc->done = conv;
          sc->prev_obj = obj;
          sc->K = Knew;
          sc->it = sc->it + 1;
        }
      }
    }
    gbarO(bcnt, bgen);
  }
}

// ---------------- host ----------------

extern "C" void kernel_launch(void* const* d_in, const int* in_sizes, int n_in,
                              void* d_out, int out_size, void* d_ws, size_t ws_size,
                              hipStream_t stream) {
  const float* X = (const float*)d_in[0];
  float* mu = (float*)d_out;                   // 64 x 1024 fp32 output
  char* ws = (char*)d_ws;
  float*  x2    = (float*)(ws + 0);            // 256 KB
  int*    z     = (int*)(ws + 262144);         // 256 KB
  double* sums  = (double*)(ws + 524288);      // 512 KB
  double* musum = (double*)(ws + 1048576);     // 8 KB
  float*  m2f   = (float*)(ws + 1056768);      // 256 B
  Scal*   sc    = (Scal*)(ws + 1057024);       // ~600 B
  int*    bar   = (int*)(ws + 1058048);        // 8 KB (tree barrier)
  float*  XT    = (float*)(ws + (size_t)(2u << 20));  // 268.4 MB transposed X

  const size_t need = (size_t)(2u << 20) + (size_t)DDIM * NPTS * sizeof(float);

  kInit<<<1, 1024, 0, stream>>>(bar);
  if (ws_size >= need)
    kMainT<<<GRID, 256, 0, stream>>>(X, mu, x2, z, sums, musum, m2f, sc, bar, XT);
  else
    kMainOld<<<GRID, 256, 0, stream>>>(X, mu, x2, z, sums, musum, m2f, sc, bar);
}